// Round 4
// baseline (247.421 us; speedup 1.0000x reference)
//
#include <hip/hip_runtime.h>
#include <math.h>

// CellSegmentationLoss: fused focal + dice + boundary-BCE + IoU-aux loss.
// Inputs: d_in[0]=pred_masks (16*1*1024*1024 f32), d_in[1]=gt_masks (same),
//         d_in[2]=pred_iou (16 f32). Output: 1 f32 scalar.
//
// R7: R3's register regime + single-generation geometry.
// Ledger:
//   R3 (46us): bounds(256,4), VGPR=60, NO spill -- but 2048 blocks = two
//              generations at 4 blk/CU, drain between them (occ 30%).
//   R4 (56us): tiny blocks, per-block overhead + atomic contention.
//   R5 (288us), R6 (124us): bounds(256,8) => 64-VGPR cap => the load window
//              SPILLED to scratch (WRITE_SIZE 186-194 MB) and the scratch
//              traffic evicted inputs from L3 (FETCH 65->158 MB).
// Conclusion: occupancy-8 is unreachable without destroying the register
// pipeline. Operate at the proven 128-VGPR cap and fix geometry instead:
//   - 1024 blocks = exactly 4/CU, ONE generation, no mid-kernel drain
//   - 16384 px/block (16 float4/thread/array), loads adjacent to use,
//     full unroll, NO sched_barrier, NO hand prefetch (R5 lesson)

#define HW_PIX (1024 * 1024)
#define BATCH 16
constexpr int THREADS = 256;
constexpr int BLOCKS = 1024;                            // 4 / CU, 1 generation
constexpr int BLOCKS_PER_IMG = BLOCKS / BATCH;          // 64
constexpr int PIX_PER_BLOCK = HW_PIX / BLOCKS_PER_IMG;  // 16384
constexpr int F4_PER_THREAD = PIX_PER_BLOCK / (THREADS * 4);  // 16

struct Accum {
  float fsum, csum, isum, psum;
  unsigned tcnt, bicnt, bpcnt;
};

__device__ __forceinline__ void process4(const float4 xv, const float4 tv,
                                         Accum& a) {
  const float* xs = reinterpret_cast<const float*>(&xv);
  const float* ts = reinterpret_cast<const float*>(&tv);
#pragma unroll
  for (int j = 0; j < 4; ++j) {
    const float xx = xs[j];
    const float tt = ts[j];
    const float e = __expf(-fabsf(xx));                // exp(-|x|) in (0,1]
    const float s = 1.0f + e;
    const float r = __builtin_amdgcn_rcpf(s);
    const float p = (xx >= 0.0f) ? r : e * r;          // sigmoid(x)
    const float ce = fmaxf(xx, 0.0f) - xx * tt + __logf(s);
    const float om = fmaf(tt, 1.0f - 2.0f * p, p);     // 1 - p_t
    const float at = 0.75f - 0.5f * tt;                // alpha_t
    a.fsum += at * ce * om * om;
    a.csum += ce;
    a.isum = fmaf(p, tt, a.isum);
    a.psum += p;
    const unsigned long long mt = __ballot(tt != 0.0f);
    const unsigned long long mb = __ballot(xx > 0.0f); // p>0.5 <=> x>0
    a.tcnt  += (unsigned)__popcll(mt);
    a.bpcnt += (unsigned)__popcll(mb);
    a.bicnt += (unsigned)__popcll(mt & mb);
  }
}

__global__ __launch_bounds__(THREADS, 4) void
loss_partial(const float* __restrict__ x, const float* __restrict__ t,
             float* __restrict__ acc) {
  const int b = blockIdx.x / BLOCKS_PER_IMG;
  const long base = (long)blockIdx.x * PIX_PER_BLOCK;
  const float4* __restrict__ x4 = (const float4*)(x + base);
  const float4* __restrict__ t4 = (const float4*)(t + base);
  const int tid = threadIdx.x;

  Accum a = {0.f, 0.f, 0.f, 0.f, 0u, 0u, 0u};

  // Plain unrolled stream, loads adjacent to use. Under the 128-VGPR cap
  // the scheduler hoists these into a deep outstanding window on its own
  // (R3: VGPR=60, counted vmcnt waits, zero spill). Do NOT force it.
#pragma unroll
  for (int i = 0; i < F4_PER_THREAD; i += 2) {
    const float4 x0 = x4[tid + (i + 0) * THREADS];
    const float4 t0 = t4[tid + (i + 0) * THREADS];
    const float4 x1 = x4[tid + (i + 1) * THREADS];
    const float4 t1 = t4[tid + (i + 1) * THREADS];
    process4(x0, t0, a);
    process4(x1, t1, a);
  }

  __shared__ float red[THREADS / 64][7];
  const int lane = threadIdx.x & 63;
  const int wave = threadIdx.x >> 6;
  float vals[4] = {a.fsum, a.csum, a.isum, a.psum};
#pragma unroll
  for (int k = 0; k < 4; ++k) {
    float v = vals[k];
#pragma unroll
    for (int off = 32; off > 0; off >>= 1) v += __shfl_down(v, off);
    if (lane == 0) red[wave][k] = v;
  }
  if (lane == 0) {                 // counts are already wave totals
    red[wave][4] = (float)a.tcnt;
    red[wave][5] = (float)a.bicnt;
    red[wave][6] = (float)a.bpcnt;
  }
  __syncthreads();
  if (threadIdx.x < 7) {
    const float s = red[0][threadIdx.x] + red[1][threadIdx.x] +
                    red[2][threadIdx.x] + red[3][threadIdx.x];
    atomicAdd(&acc[b * 16 + threadIdx.x], s);  // stride 16: own line/image
  }
}

__global__ void loss_final(const float* __restrict__ acc,
                           const float* __restrict__ pred_iou,
                           float* __restrict__ out) {
  constexpr float SMOOTH = 1e-6f;
  const int lane = threadIdx.x;  // one wave (64), lanes 0..15 active
  float F = 0.f, C = 0.f, D = 0.f, Q = 0.f;
  if (lane < BATCH) {
    const float* a = acc + lane * 16;
    F = a[0];
    C = a[1];
    const float I = a[2], P = a[3], T = a[4], BI = a[5], BP = a[6];
    D = (2.0f * I + SMOOTH) / (P + T + SMOOTH);            // dice term
    const float iou = (BI + SMOOTH) / (BP + T - BI + SMOOTH);
    const float d = pred_iou[lane] - iou;
    Q = d * d;
  }
#pragma unroll
  for (int off = 32; off > 0; off >>= 1) {
    F += __shfl_down(F, off);
    C += __shfl_down(C, off);
    D += __shfl_down(D, off);
    Q += __shfl_down(Q, off);
  }
  if (lane == 0) {
    const float invN = 1.0f / (float)((long)BATCH * HW_PIX);
    const float focal = F * invN;
    const float dice = 1.0f - D * (1.0f / (float)BATCH);
    const float half_boundary = C * invN;  // 0.5 * (2.0 * mean(ce))
    const float iou_loss = Q * (1.0f / (float)BATCH);
    out[0] = focal + dice + half_boundary + 0.1f * iou_loss;
  }
}

extern "C" void kernel_launch(void* const* d_in, const int* in_sizes, int n_in,
                              void* d_out, int out_size, void* d_ws,
                              size_t ws_size, hipStream_t stream) {
  const float* x = (const float*)d_in[0];
  const float* t = (const float*)d_in[1];
  const float* piou = (const float*)d_in[2];
  float* acc = (float*)d_ws;  // BATCH*16 floats

  hipMemsetAsync(acc, 0, BATCH * 16 * sizeof(float), stream);
  loss_partial<<<BLOCKS, THREADS, 0, stream>>>(x, t, acc);
  loss_final<<<1, 64, 0, stream>>>(acc, piou, (float*)d_out);
}

// Round 5
// 153.349 us; speedup vs baseline: 1.6134x; 1.6134x over previous
//
#include <hip/hip_runtime.h>
#include <math.h>

// CellSegmentationLoss: fused focal + dice + boundary-BCE + IoU-aux loss.
// Inputs: d_in[0]=pred_masks (16*1*1024*1024 f32), d_in[1]=gt_masks (same),
//         d_in[2]=pred_iou (16 f32). Output: 1 f32 scalar.
//
// R8: ROLLED main loop (the one non-spilling steady-state structure).
// Ledger:
//   R3 (46us): one-shot 16-load burst, VGPR=60, no spill, occ 30% (2 gens).
//   R4 (56us): 2048px micro-blocks, per-block overhead + shallow windows.
//   R5 (288us)/R6 (124us)/R7 (135us): every FULLY-UNROLLED load stream got
//       hoisted into 128+ live VGPRs and SPILLED (WRITE_SIZE 157-194 MB),
//       regardless of launch_bounds (allocator self-caps at 64).
// Fix: #pragma unroll 1 loop, 4 dwordx4 loads per body -> bounded footprint
// (~50 VGPR, spill impossible), continuous load issue for the wave's whole
// life; 1024 blocks = 4/CU, ONE generation (R7 geometry, now un-spilled);
// ballot/popc -> float accumulation (tt is exactly 0/1; counts <=64 exact).

#define HW_PIX (1024 * 1024)
#define BATCH 16
constexpr int THREADS = 256;
constexpr int BLOCKS = 1024;                            // 4 / CU, 1 generation
constexpr int BLOCKS_PER_IMG = BLOCKS / BATCH;          // 64
constexpr int PIX_PER_BLOCK = HW_PIX / BLOCKS_PER_IMG;  // 16384
constexpr int F4_PER_THREAD = PIX_PER_BLOCK / (THREADS * 4);  // 16
constexpr int LOOP_ITERS = F4_PER_THREAD / 2;           // 8 (2 f4/array/iter)

struct Accum {
  float fsum, csum, isum, psum;
  float tcnt, bicnt, bpcnt;   // counts as floats: exact for <=2^24
};

__device__ __forceinline__ void process4(const float4 xv, const float4 tv,
                                         Accum& a) {
  const float* xs = reinterpret_cast<const float*>(&xv);
  const float* ts = reinterpret_cast<const float*>(&tv);
#pragma unroll
  for (int j = 0; j < 4; ++j) {
    const float xx = xs[j];
    const float tt = ts[j];
    const float e = __expf(-fabsf(xx));                // exp(-|x|) in (0,1]
    const float s = 1.0f + e;
    const float r = __builtin_amdgcn_rcpf(s);
    const float p = (xx >= 0.0f) ? r : e * r;          // sigmoid(x)
    const float ce = fmaxf(xx, 0.0f) - xx * tt + __logf(s);
    const float om = fmaf(tt, 1.0f - 2.0f * p, p);     // 1 - p_t
    const float at = 0.75f - 0.5f * tt;                // alpha_t
    a.fsum += at * ce * om * om;
    a.csum += ce;
    a.isum = fmaf(p, tt, a.isum);
    a.psum += p;
    const float pb = (xx > 0.0f) ? 1.0f : 0.0f;        // p>0.5 <=> x>0
    a.tcnt += tt;                                      // tt in {0,1}
    a.bpcnt += pb;
    a.bicnt += pb * tt;
  }
}

__global__ __launch_bounds__(THREADS, 4) void
loss_partial(const float* __restrict__ x, const float* __restrict__ t,
             float* __restrict__ acc) {
  const int b = blockIdx.x / BLOCKS_PER_IMG;
  const long base = (long)blockIdx.x * PIX_PER_BLOCK;
  const float4* __restrict__ x4 = (const float4*)(x + base);
  const float4* __restrict__ t4 = (const float4*)(t + base);
  const int tid = threadIdx.x;

  Accum a = {0.f, 0.f, 0.f, 0.f, 0.f, 0.f, 0.f};

  // ROLLED loop: 4 dwordx4 loads per body. Small fixed footprint -> the
  // hoist-then-spill failure mode of R5/R6/R7 is structurally impossible,
  // while load issue stays continuous across the wave's lifetime.
#pragma unroll 1
  for (int i = 0; i < LOOP_ITERS; ++i) {
    const float4 x0 = x4[tid + (2 * i + 0) * THREADS];
    const float4 t0 = t4[tid + (2 * i + 0) * THREADS];
    const float4 x1 = x4[tid + (2 * i + 1) * THREADS];
    const float4 t1 = t4[tid + (2 * i + 1) * THREADS];
    process4(x0, t0, a);
    process4(x1, t1, a);
  }

  __shared__ float red[THREADS / 64][7];
  const int lane = threadIdx.x & 63;
  const int wave = threadIdx.x >> 6;
  const float vals[7] = {a.fsum, a.csum, a.isum, a.psum,
                         a.tcnt, a.bicnt, a.bpcnt};
#pragma unroll
  for (int k = 0; k < 7; ++k) {
    float v = vals[k];
#pragma unroll
    for (int off = 32; off > 0; off >>= 1) v += __shfl_down(v, off);
    if (lane == 0) red[wave][k] = v;
  }
  __syncthreads();
  if (threadIdx.x < 7) {
    const float s = red[0][threadIdx.x] + red[1][threadIdx.x] +
                    red[2][threadIdx.x] + red[3][threadIdx.x];
    atomicAdd(&acc[b * 16 + threadIdx.x], s);  // stride 16: own line/image
  }
}

__global__ void loss_final(const float* __restrict__ acc,
                           const float* __restrict__ pred_iou,
                           float* __restrict__ out) {
  constexpr float SMOOTH = 1e-6f;
  const int lane = threadIdx.x;  // one wave (64), lanes 0..15 active
  float F = 0.f, C = 0.f, D = 0.f, Q = 0.f;
  if (lane < BATCH) {
    const float* a = acc + lane * 16;
    F = a[0];
    C = a[1];
    const float I = a[2], P = a[3], T = a[4], BI = a[5], BP = a[6];
    D = (2.0f * I + SMOOTH) / (P + T + SMOOTH);            // dice term
    const float iou = (BI + SMOOTH) / (BP + T - BI + SMOOTH);
    const float d = pred_iou[lane] - iou;
    Q = d * d;
  }
#pragma unroll
  for (int off = 32; off > 0; off >>= 1) {
    F += __shfl_down(F, off);
    C += __shfl_down(C, off);
    D += __shfl_down(D, off);
    Q += __shfl_down(Q, off);
  }
  if (lane == 0) {
    const float invN = 1.0f / (float)((long)BATCH * HW_PIX);
    const float focal = F * invN;
    const float dice = 1.0f - D * (1.0f / (float)BATCH);
    const float half_boundary = C * invN;  // 0.5 * (2.0 * mean(ce))
    const float iou_loss = Q * (1.0f / (float)BATCH);
    out[0] = focal + dice + half_boundary + 0.1f * iou_loss;
  }
}

extern "C" void kernel_launch(void* const* d_in, const int* in_sizes, int n_in,
                              void* d_out, int out_size, void* d_ws,
                              size_t ws_size, hipStream_t stream) {
  const float* x = (const float*)d_in[0];
  const float* t = (const float*)d_in[1];
  const float* piou = (const float*)d_in[2];
  float* acc = (float*)d_ws;  // BATCH*16 floats

  hipMemsetAsync(acc, 0, BATCH * 16 * sizeof(float), stream);
  loss_partial<<<BLOCKS, THREADS, 0, stream>>>(x, t, acc);
  loss_final<<<1, 64, 0, stream>>>(acc, piou, (float*)d_out);
}